// Round 5
// baseline (2208.797 us; speedup 1.0000x reference)
//
#include <hip/hip_runtime.h>
#include <hip/hip_bf16.h>
#include <math.h>

// Shapes (fixed by the reference)
#define B_   128
#define W_   512
#define D_   2048
#define H_   16
#define DH_  128

typedef __attribute__((ext_vector_type(4))) float f32x4;
typedef __attribute__((ext_vector_type(8))) short bf16x8;

__device__ inline short f2bf(float f) {
  union { __hip_bfloat16 h; short s; } u;
  u.h = __float2bfloat16(f);
  return u.s;
}
__device__ inline float bf2f(unsigned short u) {
  return __uint_as_float(((unsigned)u) << 16);
}

// raw barrier: drain LDS ops but NOT in-flight global loads (vmcnt).
#define LGKM_BARRIER() do {                                   \
    asm volatile("s_waitcnt lgkmcnt(0)" ::: "memory");        \
    __builtin_amdgcn_sched_barrier(0);                        \
    __builtin_amdgcn_s_barrier();                             \
    __builtin_amdgcn_sched_barrier(0);                        \
  } while (0)

// ---------------------------------------------------------------------------
// bf16 MFMA GEMM, M = 128 always.  C[m,n] = sum_k A[m,k] * B[n,k].
// (unchanged from R3)
// ---------------------------------------------------------------------------
template<bool BBF16>
__global__ __launch_bounds__(256) void gemm_mfma(
    const float* __restrict__ A, int a_rs, long a_hs,
    const float* __restrict__ A2, int a2_k,
    const void* __restrict__ Bv, int b_rs, long b_hs,
    float* __restrict__ C, int c_rs, long c_hs, long c_ks,
    int Kblk)
{
  __shared__ char sm[2][24576];

  const int t  = threadIdx.x;
  const int w  = t >> 6, l = t & 63, lo = l & 15, hi = l >> 4;
  const int wm = w >> 1, wn = w & 1;
  const int n0   = blockIdx.x * 64;
  const int head = blockIdx.y;
  const int ks   = blockIdx.z;
  const int kbeg = ks * Kblk;
  const int nit  = Kblk >> 6;

  const float* Ab;
  {
    const float* base = A;
    int koff = kbeg;
    if (A2 && kbeg >= a2_k) { base = A2; koff = kbeg - a2_k; }
    Ab = base + head * a_hs + koff;
  }
  const float*          Bf = (const float*)Bv          + (BBF16 ? 0 : head * b_hs + (long)n0 * b_rs + kbeg);
  const unsigned short* Bh = (const unsigned short*)Bv + (BBF16 ? head * b_hs + (long)n0 * b_rs + kbeg : 0);

  const int ar = t >> 2;
  const int ak = (t & 3) * 16;

  f32x4 acc[4][2] = {};

  auto load_tiles = [&](int it, float4* ar4, float4* br4) {
    const float* Ait = Ab + it * 64;
#pragma unroll
    for (int p = 0; p < 2; ++p) {
      const float* src = Ait + (long)(p * 64 + ar) * a_rs + ak;
#pragma unroll
      for (int qq = 0; qq < 4; ++qq) ar4[p * 4 + qq] = *(const float4*)(src + qq * 4);
    }
    if (BBF16) {
      const char* src = (const char*)(Bh + (long)ar * b_rs + it * 64 + ak);
      br4[0] = *(const float4*)(src);
      br4[1] = *(const float4*)(src + 16);
    } else {
      const float* src = Bf + (long)ar * b_rs + it * 64 + ak;
#pragma unroll
      for (int qq = 0; qq < 4; ++qq) br4[qq] = *(const float4*)(src + qq * 4);
    }
  };

  auto write_tiles = [&](int buf, const float4* ar4, const float4* br4) {
    char* As = sm[buf];
    char* Bs = sm[buf] + 16384;
#pragma unroll
    for (int p = 0; p < 2; ++p) {
      int m = p * 64 + ar;
      int base = m * 128 + ak * 2;
      int swz = (m & 7) << 4;
#pragma unroll
      for (int h2 = 0; h2 < 2; ++h2) {
        bf16x8 v;
        const float* f = (const float*)(ar4 + p * 4);
#pragma unroll
        for (int j = 0; j < 8; ++j) v[j] = f2bf(f[h2 * 8 + j]);
        *(bf16x8*)(As + ((base + h2 * 16) ^ swz)) = v;
      }
    }
    {
      int n = ar;
      int base = n * 128 + ak * 2;
      int swz = (n & 7) << 4;
      if (BBF16) {
#pragma unroll
        for (int h2 = 0; h2 < 2; ++h2)
          *(bf16x8*)(Bs + ((base + h2 * 16) ^ swz)) = ((const bf16x8*)br4)[h2];
      } else {
#pragma unroll
        for (int h2 = 0; h2 < 2; ++h2) {
          bf16x8 v;
          const float* f = (const float*)br4;
#pragma unroll
          for (int j = 0; j < 8; ++j) v[j] = f2bf(f[h2 * 8 + j]);
          *(bf16x8*)(Bs + ((base + h2 * 16) ^ swz)) = v;
        }
      }
    }
  };

  auto compute = [&](int buf) {
    const char* As = sm[buf];
    const char* Bs = sm[buf] + 16384;
#pragma unroll
    for (int kk = 0; kk < 2; ++kk) {
      bf16x8 af[4], bfr[2];
#pragma unroll
      for (int mi = 0; mi < 4; ++mi) {
        int m = wm * 64 + mi * 16 + lo;
        af[mi] = *(const bf16x8*)(As + ((m * 128 + (kk * 32 + hi * 8) * 2) ^ ((m & 7) << 4)));
      }
#pragma unroll
      for (int ni = 0; ni < 2; ++ni) {
        int n = wn * 32 + ni * 16 + lo;
        bfr[ni] = *(const bf16x8*)(Bs + ((n * 128 + (kk * 32 + hi * 8) * 2) ^ ((n & 7) << 4)));
      }
#pragma unroll
      for (int mi = 0; mi < 4; ++mi)
#pragma unroll
        for (int ni = 0; ni < 2; ++ni)
          acc[mi][ni] = __builtin_amdgcn_mfma_f32_16x16x32_bf16(af[mi], bfr[ni], acc[mi][ni], 0, 0, 0);
    }
  };

  float4 ar4[8], br4[4];
  load_tiles(0, ar4, br4);
  write_tiles(0, ar4, br4);
  __syncthreads();
  for (int it = 0; it < nit; ++it) {
    float4 na[8], nb[4];
    if (it + 1 < nit) load_tiles(it + 1, na, nb);
    compute(it & 1);
    if (it + 1 < nit) write_tiles((it + 1) & 1, na, nb);
    __syncthreads();
  }

  float* Cb = C + c_ks * ks + c_hs * head + n0;
#pragma unroll
  for (int mi = 0; mi < 4; ++mi)
#pragma unroll
    for (int ni = 0; ni < 2; ++ni)
#pragma unroll
      for (int r = 0; r < 4; ++r)
        Cb[(long)(wm * 64 + mi * 16 + hi * 4 + r) * c_rs + (wn * 32 + ni * 16 + lo)] = acc[mi][ni][r];
}

// ---------------------------------------------------------------------------
// WkT[h][e][d] (bf16) = Wk[h*128+d][e].  (unchanged)
// ---------------------------------------------------------------------------
__global__ __launch_bounds__(256) void transpose_wk(
    const float* __restrict__ Wk, unsigned short* __restrict__ WkT)
{
  __shared__ float tile[64][68];
  const int t  = threadIdx.x;
  const int e0 = blockIdx.x * 64;
  const int d0 = blockIdx.y * 64;
  const int h  = blockIdx.z;
  {
    int d = t >> 2, eq = (t & 3) * 16;
    const float* src = Wk + (long)(h * DH_ + d0 + d) * D_ + e0 + eq;
#pragma unroll
    for (int qq = 0; qq < 4; ++qq)
      *(float4*)&tile[d][eq + qq * 4] = *(const float4*)(src + qq * 4);
  }
  __syncthreads();
  {
    int e = t >> 2, dq = (t & 3) * 16;
    unsigned short* dst = WkT + ((long)h * D_ + e0 + e) * DH_ + d0 + dq;
    bf16x8 v0, v1;
#pragma unroll
    for (int j = 0; j < 8; ++j) v0[j] = f2bf(tile[dq + j][e]);
#pragma unroll
    for (int j = 0; j < 8; ++j) v1[j] = f2bf(tile[dq + 8 + j][e]);
    *(bf16x8*)dst = v0;
    *(bf16x8*)(dst + 8) = v1;
  }
}

// ---------------------------------------------------------------------------
__global__ void reduce_add_k(const float* __restrict__ part, int ns, long stride,
                             long n, float* __restrict__ out)
{
  for (long i = (long)blockIdx.x * blockDim.x + threadIdx.x; i < n;
       i += (long)gridDim.x * blockDim.x) {
    float s = 0.f;
    for (int k = 0; k < ns; ++k) s += part[k * stride + i];
    out[i] = s;
  }
}

// ---------------------------------------------------------------------------
// Fused flash attention v2: 16-row bf16 KV tiles, reg-staged (perm-pack
// truncation), logits MFMA straight from bf16 LDS, partial-store + 4-wave
// reduce/softmax (no LDS atomics), VALU PV on unpacked bf16.
// grid (128 b, 2 s-halves), block 1024 (16 waves); wave w: e-band 128w..+128,
// stages row s_loc = w of each tile.
// ---------------------------------------------------------------------------
__global__ __launch_bounds__(1024) void fused_attn(
    const float* __restrict__ x, const float* __restrict__ buffer,
    const float* __restrict__ qt, unsigned short* __restrict__ part,
    float* __restrict__ ml)
{
  __shared__ unsigned short kv[2][16 * 2048];   // 128 KiB bf16, row-XOR swz
  __shared__ float lacc[16][16][16];            // partials [wave][h][s], 16 KiB
  __shared__ float pbuf[16][16];                // P fp32 [h][s]
  __shared__ float sbuf[16];                    // per-h rescale

  const int b    = blockIdx.x;
  const int half = blockIdx.y;
  const int t    = threadIdx.x;
  const int w    = t >> 6;
  const int l    = t & 63;
  const int lo   = l & 15;
  const int hi   = l >> 4;

  // q~ A-frags for this wave's e-band (scale folded), bf16 RNE (once)
  bf16x8 afrag[4];
  {
    const float* qrow = qt + ((long)b * H_ + lo) * D_;
    const float sc = 0.088388347648318447f;   // 1/sqrt(128)
#pragma unroll
    for (int kk = 0; kk < 4; ++kk) {
      int e0 = w * 128 + kk * 32 + hi * 8;
#pragma unroll
      for (int j = 0; j < 8; ++j) afrag[kk][j] = f2bf(qrow[e0 + j] * sc);
    }
  }

  float accE[16][2];
#pragma unroll
  for (int h = 0; h < 16; ++h) { accE[h][0] = 0.f; accE[h][1] = 0.f; }
  float m_run = -1e30f, l_run = 0.f;   // live in waves 0-3 (4 heads each)

  float4 st[8];   // staged fp32 row segment (32 floats)

  auto stage_load = [&](int tl) {
    int s_glob = half * 256 + tl * 16 + w;
    const float* row = (s_glob < W_ - 1)
        ? buffer + (((long)(b * W_ + s_glob + 1)) << 11)
        : x + ((long)b << 11);
#pragma unroll
    for (int c = 0; c < 4; ++c) {
      const float* p = row + c * 512 + l * 8;
      st[c * 2]     = *(const float4*)p;
      st[c * 2 + 1] = *(const float4*)(p + 4);
    }
  };

  // truncation-pack fp32->bf16 (v_perm) and write row w with XOR swizzle
  auto pack_write = [&](int bufi) {
    char* dst = (char*)kv[bufi] + w * 4096;
    const unsigned swz = (unsigned)((w & 7) << 4);
#pragma unroll
    for (int c = 0; c < 4; ++c) {
      unsigned u[4];
      const float* f = (const float*)&st[c * 2];
#pragma unroll
      for (int j = 0; j < 4; ++j)
        u[j] = __builtin_amdgcn_perm(__float_as_uint(f[2 * j + 1]),
                                     __float_as_uint(f[2 * j]), 0x07060302u);
      *(uint4*)(dst + (((unsigned)(c * 1024 + l * 16)) ^ swz)) = *(const uint4*)u;
    }
  };

  // prologue: tile 0 resident, tile 1 in flight
  stage_load(0);
  pack_write(0);          // compiler inserts the vmcnt wait
  LGKM_BARRIER();
  stage_load(1);

  for (int tile = 0; tile < 16; ++tile) {
    const int bufi = tile & 1;
    const char* kb = (const char*)kv[bufi];

    // ---- logits: per-wave e-band partial via MFMA (bf16 frags direct)
    {
      f32x4 c4 = {0.f, 0.f, 0.f, 0.f};
      const char* rowp = kb + lo * 4096;
      const unsigned swz = (unsigned)((lo & 7) << 4);
#pragma unroll
      for (int kk = 0; kk < 4; ++kk) {
        bf16x8 bv = *(const bf16x8*)(rowp + (((unsigned)(w * 256 + kk * 64 + hi * 16)) ^ swz));
        c4 = __builtin_amdgcn_mfma_f32_16x16x32_bf16(afrag[kk], bv, c4, 0, 0, 0);
      }
#pragma unroll
      for (int r = 0; r < 4; ++r) lacc[w][hi * 4 + r][lo] = c4[r];
    }
    LGKM_BARRIER();                    // B1: partials visible

    // ---- reduce + online softmax: waves 0-3, wave wr owns h = wr*4+hi
    if (w < 4) {
      const int h = w * 4 + hi, s = lo;
      float v = 0.f;
#pragma unroll
      for (int ww = 0; ww < 16; ++ww) v += lacc[ww][h][s];
      float mt = v;
      mt = fmaxf(mt, __shfl_xor(mt, 1));
      mt = fmaxf(mt, __shfl_xor(mt, 2));
      mt = fmaxf(mt, __shfl_xor(mt, 4));
      mt = fmaxf(mt, __shfl_xor(mt, 8));
      float m_new = fmaxf(m_run, mt);
      float scl = __expf(m_run - m_new);
      float p = __expf(v - m_new);
      float ps = p;
      ps += __shfl_xor(ps, 1);
      ps += __shfl_xor(ps, 2);
      ps += __shfl_xor(ps, 4);
      ps += __shfl_xor(ps, 8);
      l_run = l_run * scl + ps;
      m_run = m_new;
      pbuf[h][s] = p;
      if (s == 0) sbuf[h] = scl;
    }
    LGKM_BARRIER();                    // B2: pbuf/sbuf ready

    // ---- PV: lane owns e = 128w + 2l, 2l+1
    {
#pragma unroll
      for (int h = 0; h < 16; ++h) {
        float scl = sbuf[h];
        accE[h][0] *= scl; accE[h][1] *= scl;
      }
      const unsigned ecol = (unsigned)(w * 256 + l * 4);
#pragma unroll
      for (int sh = 0; sh < 2; ++sh) {
        float ke[8][2];
#pragma unroll
        for (int s8 = 0; s8 < 8; ++s8) {
          int s = sh * 8 + s8;
          unsigned u = *(const unsigned*)(kb + s * 4096 + (ecol ^ ((unsigned)((s & 7) << 4))));
          ke[s8][0] = __uint_as_float(u << 16);
          ke[s8][1] = __uint_as_float(u & 0xffff0000u);
        }
#pragma unroll
        for (int h = 0; h < 16; ++h) {
          float4 pA = *(const float4*)&pbuf[h][sh * 8];
          float4 pB = *(const float4*)&pbuf[h][sh * 8 + 4];
          float a0 = accE[h][0], a1 = accE[h][1];
          a0 += pA.x * ke[0][0] + pA.y * ke[1][0] + pA.z * ke[2][0] + pA.w * ke[3][0]
              + pB.x * ke[4][0] + pB.y * ke[5][0] + pB.z * ke[6][0] + pB.w * ke[7][0];
          a1 += pA.x * ke[0][1] + pA.y * ke[1][1] + pA.z * ke[2][1] + pA.w * ke[3][1]
              + pB.x * ke[4][1] + pB.y * ke[5][1] + pB.z * ke[6][1] + pB.w * ke[7][1];
          accE[h][0] = a0; accE[h][1] = a1;
        }
      }
    }

    // write tile t+1 into the other buffer (its readers finished last iter)
    if (tile < 15) pack_write(bufi ^ 1);
    LGKM_BARRIER();                    // B3: kv(t+1) visible
    if (tile < 14) stage_load(tile + 2);   // in flight through next compute
  }

  // ---- epilogue: unnormalized acc (bf16) + (m,l)
  {
    long base = ((long)half * B_ + b) * H_;
#pragma unroll
    for (int h = 0; h < 16; ++h) {
      long idx = (base + h) * D_ + w * 128 + l * 2;
      unsigned u0 = (unsigned short)f2bf(accE[h][0]);
      unsigned u1 = (unsigned short)f2bf(accE[h][1]);
      *(unsigned*)(part + idx) = u0 | (u1 << 16);
    }
    if (w < 4 && lo == 0) {
      ml[(base + w * 4 + hi) * 2 + 0] = m_run;
      ml[(base + w * 4 + hi) * 2 + 1] = l_run;
    }
  }
}

// ---------------------------------------------------------------------------
__global__ __launch_bounds__(256) void combine_k(
    const unsigned short* __restrict__ part, const float* __restrict__ ml,
    float* __restrict__ vt)
{
  const int bh = blockIdx.x;
  const float m0 = ml[bh * 2],          l0 = ml[bh * 2 + 1];
  const float m1 = ml[(2048 + bh) * 2], l1 = ml[(2048 + bh) * 2 + 1];
  const float M  = fmaxf(m0, m1);
  const float w0 = __expf(m0 - M), w1 = __expf(m1 - M);
  const float inv = 1.0f / (w0 * l0 + w1 * l1);
  const unsigned short* p0 = part + (long)bh * D_;
  const unsigned short* p1 = part + (long)(2048 + bh) * D_;
  float* out = vt + (long)bh * D_;

  const int e = threadIdx.x * 8;
  ushort4 a1 = *(const ushort4*)(p0 + e);
  ushort4 a2 = *(const ushort4*)(p0 + e + 4);
  ushort4 b1 = *(const ushort4*)(p1 + e);
  ushort4 b2 = *(const ushort4*)(p1 + e + 4);
  float oa[8], ob[8];
  oa[0]=bf2f(a1.x); oa[1]=bf2f(a1.y); oa[2]=bf2f(a1.z); oa[3]=bf2f(a1.w);
  oa[4]=bf2f(a2.x); oa[5]=bf2f(a2.y); oa[6]=bf2f(a2.z); oa[7]=bf2f(a2.w);
  ob[0]=bf2f(b1.x); ob[1]=bf2f(b1.y); ob[2]=bf2f(b1.z); ob[3]=bf2f(b1.w);
  ob[4]=bf2f(b2.x); ob[5]=bf2f(b2.y); ob[6]=bf2f(b2.z); ob[7]=bf2f(b2.w);
#pragma unroll
  for (int j = 0; j < 8; ++j) out[e + j] = (w0 * oa[j] + w1 * ob[j]) * inv;
}

// ---------------------------------------------------------------------------
__global__ __launch_bounds__(256) void gate_final_k(
    const float* __restrict__ part, const float* __restrict__ bg,
    const float* __restrict__ x, const float* __restrict__ out1,
    float* __restrict__ y)
{
  const long i = (long)blockIdx.x * 256 + threadIdx.x;
  float z = bg[i & (D_ - 1)];
#pragma unroll
  for (int k = 0; k < 8; ++k) z += part[(long)k * (B_ * D_) + i];
  const float g = 1.0f / (1.0f + expf(-z));
  y[i] = x[i] + g * out1[i];
}

// ---------------------------------------------------------------------------
extern "C" void kernel_launch(void* const* d_in, const int* in_sizes, int n_in,
                              void* d_out, int out_size, void* d_ws, size_t ws_size,
                              hipStream_t stream)
{
  const float* x      = (const float*)d_in[0];
  const float* buffer = (const float*)d_in[1];
  const float* Wq     = (const float*)d_in[2];
  const float* Wk     = (const float*)d_in[3];
  const float* Wv     = (const float*)d_in[4];
  const float* Wo     = (const float*)d_in[5];
  const float* Wg     = (const float*)d_in[6];
  const float* bg     = (const float*)d_in[7];
  float* y = (float*)d_out;

  // workspace layout (float units)
  float* ws    = (float*)d_ws;
  float* q     = ws;                        // 262144
  float* qt    = ws + 262144;               // 4194304 (vt aliases after fused)
  float* vt    = qt;
  unsigned short* part_a = (unsigned short*)(ws + 4456448); // 8388608 bf16
  float* ml    = ws + 8650752;              // 8192
  float* o0    = ws + 8658944;              // 262144
  float* o1    = ws + 8921088;              // 262144
  float* partg = ws + 9183232;              // 8 * 262144 = 2097152
  unsigned short* wkT = (unsigned short*)(ws + 11280384);   // 16*2048*128 bf16

  const long S = (long)B_ * D_;

  // 0) WkT[h][e][d] bf16
  transpose_wk<<<dim3(32, 2, 16), 256, 0, stream>>>(Wk, wkT);

  // 1) q = x @ Wq.T   (K=2048, ksplit 8)
  gemm_mfma<false><<<dim3(32, 1, 8), 256, 0, stream>>>(
      x, D_, 0, nullptr, 1 << 30, Wq, D_, 0, partg, D_, 0, S, 256);
  reduce_add_k<<<512, 256, 0, stream>>>(partg, 8, S, S, q);

  // 2) qt[b,h,e] = sum_d q[b,h*128+d] * WkT[h][e][d]   (K=128, per-head)
  gemm_mfma<true><<<dim3(32, 16, 1), 256, 0, stream>>>(
      q, D_, DH_, nullptr, 1 << 30, wkT, DH_, (long)D_ * DH_,
      qt, H_ * D_, D_, 0, DH_);

  // 3) fused flash attention + combine
  fused_attn<<<dim3(B_, 2), 1024, 0, stream>>>(x, buffer, qt, part_a, ml);
  combine_k<<<B_ * H_, 256, 0, stream>>>(part_a, ml, vt);

  // 4) o0[b,h*128+d] = sum_e vt[b,h,e] * Wv[h*128+d,e]  (K=2048, per-head n)
  gemm_mfma<false><<<dim3(2, 16, 8), 256, 0, stream>>>(
      vt, H_ * D_, D_, nullptr, 1 << 30, Wv, D_, (long)DH_ * D_,
      partg, D_, DH_, S, 256);
  reduce_add_k<<<512, 256, 0, stream>>>(partg, 8, S, S, o0);

  // 5) o1 = o0 @ Wo.T
  gemm_mfma<false><<<dim3(32, 1, 8), 256, 0, stream>>>(
      o0, D_, 0, nullptr, 1 << 30, Wo, D_, 0, partg, D_, 0, S, 256);
  reduce_add_k<<<512, 256, 0, stream>>>(partg, 8, S, S, o1);

  // 6) gate: z = concat(x,o1) @ Wg.T + bg   (K=4096, A-switch at 2048)
  gemm_mfma<false><<<dim3(32, 1, 8), 256, 0, stream>>>(
      x, D_, 0, o1, D_, Wg, 2 * D_, 0, partg, D_, 0, S, 512);
  gate_final_k<<<1024, 256, 0, stream>>>(partg, bg, x, o1, y);

  (void)in_sizes; (void)n_in; (void)out_size; (void)ws_size;
}

// Round 6
// 253.007 us; speedup vs baseline: 8.7302x; 8.7302x over previous
//
#include <hip/hip_runtime.h>
#include <hip/hip_bf16.h>
#include <math.h>

// Shapes (fixed by the reference)
#define B_   128
#define W_   512
#define D_   2048
#define H_   16
#define DH_  128

typedef __attribute__((ext_vector_type(4))) float f32x4;
typedef __attribute__((ext_vector_type(8))) short bf16x8;

typedef const __attribute__((address_space(1))) void* gvp;
typedef __attribute__((address_space(3))) void* lvp;

__device__ inline short f2bf(float f) {
  union { __hip_bfloat16 h; short s; } u;
  u.h = __float2bfloat16(f);
  return u.s;
}
__device__ inline float bf2f(unsigned short u) {
  return __uint_as_float(((unsigned)u) << 16);
}

// raw barrier: drain LDS ops but NOT in-flight global_load_lds (vmcnt).
#define LGKM_BARRIER() do {                                   \
    asm volatile("s_waitcnt lgkmcnt(0)" ::: "memory");        \
    __builtin_amdgcn_sched_barrier(0);                        \
    __builtin_amdgcn_s_barrier();                             \
    __builtin_amdgcn_sched_barrier(0);                        \
  } while (0)

// ---------------------------------------------------------------------------
// bf16 MFMA GEMM, M = 128 always.  C[m,n] = sum_k A[m,k] * B[n,k].
// (unchanged from R3)
// ---------------------------------------------------------------------------
template<bool BBF16>
__global__ __launch_bounds__(256) void gemm_mfma(
    const float* __restrict__ A, int a_rs, long a_hs,
    const float* __restrict__ A2, int a2_k,
    const void* __restrict__ Bv, int b_rs, long b_hs,
    float* __restrict__ C, int c_rs, long c_hs, long c_ks,
    int Kblk)
{
  __shared__ char sm[2][24576];

  const int t  = threadIdx.x;
  const int w  = t >> 6, l = t & 63, lo = l & 15, hi = l >> 4;
  const int wm = w >> 1, wn = w & 1;
  const int n0   = blockIdx.x * 64;
  const int head = blockIdx.y;
  const int ks   = blockIdx.z;
  const int kbeg = ks * Kblk;
  const int nit  = Kblk >> 6;

  const float* Ab;
  {
    const float* base = A;
    int koff = kbeg;
    if (A2 && kbeg >= a2_k) { base = A2; koff = kbeg - a2_k; }
    Ab = base + head * a_hs + koff;
  }
  const float*          Bf = (const float*)Bv          + (BBF16 ? 0 : head * b_hs + (long)n0 * b_rs + kbeg);
  const unsigned short* Bh = (const unsigned short*)Bv + (BBF16 ? head * b_hs + (long)n0 * b_rs + kbeg : 0);

  const int ar = t >> 2;
  const int ak = (t & 3) * 16;

  f32x4 acc[4][2] = {};

  auto load_tiles = [&](int it, float4* ar4, float4* br4) {
    const float* Ait = Ab + it * 64;
#pragma unroll
    for (int p = 0; p < 2; ++p) {
      const float* src = Ait + (long)(p * 64 + ar) * a_rs + ak;
#pragma unroll
      for (int qq = 0; qq < 4; ++qq) ar4[p * 4 + qq] = *(const float4*)(src + qq * 4);
    }
    if (BBF16) {
      const char* src = (const char*)(Bh + (long)ar * b_rs + it * 64 + ak);
      br4[0] = *(const float4*)(src);
      br4[1] = *(const float4*)(src + 16);
    } else {
      const float* src = Bf + (long)ar * b_rs + it * 64 + ak;
#pragma unroll
      for (int qq = 0; qq < 4; ++qq) br4[qq] = *(const float4*)(src + qq * 4);
    }
  };

  auto write_tiles = [&](int buf, const float4* ar4, const float4* br4) {
    char* As = sm[buf];
    char* Bs = sm[buf] + 16384;
#pragma unroll
    for (int p = 0; p < 2; ++p) {
      int m = p * 64 + ar;
      int base = m * 128 + ak * 2;
      int swz = (m & 7) << 4;
#pragma unroll
      for (int h2 = 0; h2 < 2; ++h2) {
        bf16x8 v;
        const float* f = (const float*)(ar4 + p * 4);
#pragma unroll
        for (int j = 0; j < 8; ++j) v[j] = f2bf(f[h2 * 8 + j]);
        *(bf16x8*)(As + ((base + h2 * 16) ^ swz)) = v;
      }
    }
    {
      int n = ar;
      int base = n * 128 + ak * 2;
      int swz = (n & 7) << 4;
      if (BBF16) {
#pragma unroll
        for (int h2 = 0; h2 < 2; ++h2)
          *(bf16x8*)(Bs + ((base + h2 * 16) ^ swz)) = ((const bf16x8*)br4)[h2];
      } else {
#pragma unroll
        for (int h2 = 0; h2 < 2; ++h2) {
          bf16x8 v;
          const float* f = (const float*)br4;
#pragma unroll
          for (int j = 0; j < 8; ++j) v[j] = f2bf(f[h2 * 8 + j]);
          *(bf16x8*)(Bs + ((base + h2 * 16) ^ swz)) = v;
        }
      }
    }
  };

  auto compute = [&](int buf) {
    const char* As = sm[buf];
    const char* Bs = sm[buf] + 16384;
#pragma unroll
    for (int kk = 0; kk < 2; ++kk) {
      bf16x8 af[4], bfr[2];
#pragma unroll
      for (int mi = 0; mi < 4; ++mi) {
        int m = wm * 64 + mi * 16 + lo;
        af[mi] = *(const bf16x8*)(As + ((m * 128 + (kk * 32 + hi * 8) * 2) ^ ((m & 7) << 4)));
      }
#pragma unroll
      for (int ni = 0; ni < 2; ++ni) {
        int n = wn * 32 + ni * 16 + lo;
        bfr[ni] = *(const bf16x8*)(Bs + ((n * 128 + (kk * 32 + hi * 8) * 2) ^ ((n & 7) << 4)));
      }
#pragma unroll
      for (int mi = 0; mi < 4; ++mi)
#pragma unroll
        for (int ni = 0; ni < 2; ++ni)
          acc[mi][ni] = __builtin_amdgcn_mfma_f32_16x16x32_bf16(af[mi], bfr[ni], acc[mi][ni], 0, 0, 0);
    }
  };

  float4 ar4[8], br4[4];
  load_tiles(0, ar4, br4);
  write_tiles(0, ar4, br4);
  __syncthreads();
  for (int it = 0; it < nit; ++it) {
    float4 na[8], nb[4];
    if (it + 1 < nit) load_tiles(it + 1, na, nb);
    compute(it & 1);
    if (it + 1 < nit) write_tiles((it + 1) & 1, na, nb);
    __syncthreads();
  }

  float* Cb = C + c_ks * ks + c_hs * head + n0;
#pragma unroll
  for (int mi = 0; mi < 4; ++mi)
#pragma unroll
    for (int ni = 0; ni < 2; ++ni)
#pragma unroll
      for (int r = 0; r < 4; ++r)
        Cb[(long)(wm * 64 + mi * 16 + hi * 4 + r) * c_rs + (wn * 32 + ni * 16 + lo)] = acc[mi][ni][r];
}

// ---------------------------------------------------------------------------
// WkT[h][e][d] (bf16) = Wk[h*128+d][e].  (unchanged)
// ---------------------------------------------------------------------------
__global__ __launch_bounds__(256) void transpose_wk(
    const float* __restrict__ Wk, unsigned short* __restrict__ WkT)
{
  __shared__ float tile[64][68];
  const int t  = threadIdx.x;
  const int e0 = blockIdx.x * 64;
  const int d0 = blockIdx.y * 64;
  const int h  = blockIdx.z;
  {
    int d = t >> 2, eq = (t & 3) * 16;
    const float* src = Wk + (long)(h * DH_ + d0 + d) * D_ + e0 + eq;
#pragma unroll
    for (int qq = 0; qq < 4; ++qq)
      *(float4*)&tile[d][eq + qq * 4] = *(const float4*)(src + qq * 4);
  }
  __syncthreads();
  {
    int e = t >> 2, dq = (t & 3) * 16;
    unsigned short* dst = WkT + ((long)h * D_ + e0 + e) * DH_ + d0 + dq;
    bf16x8 v0, v1;
#pragma unroll
    for (int j = 0; j < 8; ++j) v0[j] = f2bf(tile[dq + j][e]);
#pragma unroll
    for (int j = 0; j < 8; ++j) v1[j] = f2bf(tile[dq + 8 + j][e]);
    *(bf16x8*)dst = v0;
    *(bf16x8*)(dst + 8) = v1;
  }
}

// ---------------------------------------------------------------------------
__global__ void reduce_add_k(const float* __restrict__ part, int ns, long stride,
                             long n, float* __restrict__ out)
{
  for (long i = (long)blockIdx.x * blockDim.x + threadIdx.x; i < n;
       i += (long)gridDim.x * blockDim.x) {
    float s = 0.f;
    for (int k = 0; k < ns; ++k) s += part[k * stride + i];
    out[i] = s;
  }
}

// ---------------------------------------------------------------------------
// Fused flash attention v3 = R4 structure (fp32 KV via global_load_lds,
// 8-row double-buffered tiles) with the two serialization fixes:
//   - logits reduction via plain partial stores (one ds_write_b128/lane,
//     no LDS atomics, no zero-init)
//   - 4-wave parallel reduce + online softmax (wave wr owns heads 4wr..4wr+3)
// ---------------------------------------------------------------------------
__global__ __launch_bounds__(1024, 4) void fused_attn(
    const float* __restrict__ x, const float* __restrict__ buffer,
    const float* __restrict__ qt, unsigned short* __restrict__ part,
    float* __restrict__ ml)
{
  __shared__ float kv[2 * 8 * 2048];   // 128 KiB, two 8-row fp32 tiles
  __shared__ float lacc[16][8][16];    // partials [wave][s][h], 8 KiB
  __shared__ float pbuf[16][8];        // P fp32 [h][s]
  __shared__ float sbuf[16];           // per-h rescale factor

  const int b    = blockIdx.x;
  const int half = blockIdx.y;
  const int t    = threadIdx.x;
  const int w    = t >> 6;
  const int lane = t & 63;
  const int lo   = lane & 15;
  const int hi   = lane >> 4;
  const char* kvb = (const char*)kv;

  // q~ A-frags for this wave's e-band (scale folded in), bf16
  bf16x8 afrag[4];
  {
    const float* qrow = qt + ((long)b * H_ + lo) * D_;
    const float sc = 0.088388347648318447f;  // 1/sqrt(128)
#pragma unroll
    for (int kk = 0; kk < 4; ++kk) {
      int e0 = w * 128 + kk * 32 + hi * 8;
#pragma unroll
      for (int j = 0; j < 8; ++j) afrag[kk][j] = f2bf(qrow[e0 + j] * sc);
    }
  }

  float accE[16][2];
#pragma unroll
  for (int h = 0; h < 16; ++h) { accE[h][0] = 0.f; accE[h][1] = 0.f; }
  float m_run = -1e30f, l_run = 0.f;   // valid in waves 0-3

  auto stage = [&](int sb, int tl) {
#pragma unroll
    for (int r = 0; r < 4; ++r) {
      int s = r * 2 + (w >> 3);
      int inrow = (w & 7) * 1024 + lane * 16;
      int srco = inrow ^ (s << 4);
      int s_glob = half * 256 + tl * 8 + s;
      const float* row = (s_glob < W_ - 1)
          ? buffer + (((long)(b * W_ + s_glob + 1)) << 11)
          : x + ((long)b << 11);
      __builtin_amdgcn_global_load_lds(
          (gvp)(row + (srco >> 2)),
          (lvp)(kv + sb * 16384 + r * 4096 + w * 256), 16, 0, 0);
    }
  };

  stage(0, 0);
  __syncthreads();

  for (int tile = 0; tile < 32; ++tile) {
    const int buf  = tile & 1;
    const int bufo = buf * 65536;

    // issue next tile's loads NOW; they stay in flight across the whole
    // iteration (B1/B2 do not drain vmcnt), drained at the loop-end B3.
    if (tile + 1 < 32) stage(buf ^ 1, tile + 1);

    // ---- partial logits over this wave's e-band (MFMA)
    {
      f32x4 c4 = {0.f, 0.f, 0.f, 0.f};
      const int srow = lo & 7;   // cols 8..15 duplicate rows 0..7
#pragma unroll
      for (int kk = 0; kk < 4; ++kk) {
        unsigned B0 = (unsigned)(srow * 8192 + (w * 128 + kk * 32 + hi * 8) * 4);
        unsigned o1 = B0 ^ (unsigned)(srow << 4);
        float4 f1 = *(const float4*)(kvb + bufo + o1);
        float4 f2 = *(const float4*)(kvb + bufo + (o1 ^ 16u));
        bf16x8 bf;
        bf[0] = f2bf(f1.x); bf[1] = f2bf(f1.y); bf[2] = f2bf(f1.z); bf[3] = f2bf(f1.w);
        bf[4] = f2bf(f2.x); bf[5] = f2bf(f2.y); bf[6] = f2bf(f2.z); bf[7] = f2bf(f2.w);
        c4 = __builtin_amdgcn_mfma_f32_16x16x32_bf16(afrag[kk], bf, c4, 0, 0, 0);
      }
      // D[h=hi*4+r][s=lo]; store [w][s][h] -> contiguous in r: one b128
      if (lo < 8) *(f32x4*)&lacc[w][lo][hi * 4] = c4;
    }
    LGKM_BARRIER();                    // B1: partials visible

    // ---- reduce + online softmax: waves 0-3, wave wr owns h = wr*4+hi
    if (w < 4) {
      const int h = w * 4 + hi;
      const int s = lo & 7;            // lanes lo 8-15 duplicate lo 0-7
      float v = 0.f;
#pragma unroll
      for (int ww = 0; ww < 16; ++ww) v += lacc[ww][s][h];
      float mt = v;
      mt = fmaxf(mt, __shfl_xor(mt, 1));
      mt = fmaxf(mt, __shfl_xor(mt, 2));
      mt = fmaxf(mt, __shfl_xor(mt, 4));
      float m_new = fmaxf(m_run, mt);
      float scl = __expf(m_run - m_new);
      float p = __expf(v - m_new);
      float ps = p;
      ps += __shfl_xor(ps, 1);
      ps += __shfl_xor(ps, 2);
      ps += __shfl_xor(ps, 4);
      l_run = l_run * scl + ps;
      m_run = m_new;
      if (lo < 8) pbuf[h][s] = p;
      if (lo == 0) sbuf[h] = scl;
    }
    LGKM_BARRIER();                    // B2: pbuf/sbuf ready

    // ---- rescale + PV (fp32 VALU). lane owns e = 128w + 2*lane (+1).
    const unsigned ebyte = (unsigned)((w * 128 + lane * 2) * 4);
    float2 kvp[8];
#pragma unroll
    for (int s = 0; s < 8; ++s) {
      unsigned Bx = (unsigned)(s * 8192) + ebyte;
      kvp[s] = *(const float2*)(kvb + bufo + (Bx ^ (unsigned)(s << 4)));
    }
#pragma unroll
    for (int h = 0; h < 16; ++h) {
      float scl = sbuf[h];
      float a0 = accE[h][0] * scl, a1 = accE[h][1] * scl;
      float4 pA = *(const float4*)&pbuf[h][0];
      float4 pB = *(const float4*)&pbuf[h][4];
      a0 += pA.x * kvp[0].x + pA.y * kvp[1].x + pA.z * kvp[2].x + pA.w * kvp[3].x
          + pB.x * kvp[4].x + pB.y * kvp[5].x + pB.z * kvp[6].x + pB.w * kvp[7].x;
      a1 += pA.x * kvp[0].y + pA.y * kvp[1].y + pA.z * kvp[2].y + pA.w * kvp[3].y
          + pB.x * kvp[4].y + pB.y * kvp[5].y + pB.z * kvp[6].y + pB.w * kvp[7].y;
      accE[h][0] = a0; accE[h][1] = a1;
    }
    __syncthreads();                   // B3: vmcnt(0) drain -> tile t+1 ready
  }

  // ---- epilogue: unnormalized acc (bf16) + (m,l)
  {
    long base = ((long)half * B_ + b) * H_;
#pragma unroll
    for (int h = 0; h < 16; ++h) {
      long idx = (base + h) * D_ + w * 128 + lane * 2;
      unsigned u0 = (unsigned short)f2bf(accE[h][0]);
      unsigned u1 = (unsigned short)f2bf(accE[h][1]);
      *(unsigned*)(part + idx) = u0 | (u1 << 16);
    }
    if (w < 4 && lo == 0) {
      ml[(base + w * 4 + hi) * 2 + 0] = m_run;
      ml[(base + w * 4 + hi) * 2 + 1] = l_run;
    }
  }
}

// ---------------------------------------------------------------------------
__global__ __launch_bounds__(256) void combine_k(
    const unsigned short* __restrict__ part, const float* __restrict__ ml,
    float* __restrict__ vt)
{
  const int bh = blockIdx.x;
  const float m0 = ml[bh * 2],          l0 = ml[bh * 2 + 1];
  const float m1 = ml[(2048 + bh) * 2], l1 = ml[(2048 + bh) * 2 + 1];
  const float M  = fmaxf(m0, m1);
  const float w0 = __expf(m0 - M), w1 = __expf(m1 - M);
  const float inv = 1.0f / (w0 * l0 + w1 * l1);
  const unsigned short* p0 = part + (long)bh * D_;
  const unsigned short* p1 = part + (long)(2048 + bh) * D_;
  float* out = vt + (long)bh * D_;

  const int e = threadIdx.x * 8;
  ushort4 a1 = *(const ushort4*)(p0 + e);
  ushort4 a2 = *(const ushort4*)(p0 + e + 4);
  ushort4 b1 = *(const ushort4*)(p1 + e);
  ushort4 b2 = *(const ushort4*)(p1 + e + 4);
  float oa[8], ob[8];
  oa[0]=bf2f(a1.x); oa[1]=bf2f(a1.y); oa[2]=bf2f(a1.z); oa[3]=bf2f(a1.w);
  oa[4]=bf2f(a2.x); oa[5]=bf2f(a2.y); oa[6]=bf2f(a2.z); oa[7]=bf2f(a2.w);
  ob[0]=bf2f(b1.x); ob[1]=bf2f(b1.y); ob[2]=bf2f(b1.z); ob[3]=bf2f(b1.w);
  ob[4]=bf2f(b2.x); ob[5]=bf2f(b2.y); ob[6]=bf2f(b2.z); ob[7]=bf2f(b2.w);
#pragma unroll
  for (int j = 0; j < 8; ++j) out[e + j] = (w0 * oa[j] + w1 * ob[j]) * inv;
}

// ---------------------------------------------------------------------------
__global__ __launch_bounds__(256) void gate_final_k(
    const float* __restrict__ part, const float* __restrict__ bg,
    const float* __restrict__ x, const float* __restrict__ out1,
    float* __restrict__ y)
{
  const long i = (long)blockIdx.x * 256 + threadIdx.x;
  float z = bg[i & (D_ - 1)];
#pragma unroll
  for (int k = 0; k < 8; ++k) z += part[(long)k * (B_ * D_) + i];
  const float g = 1.0f / (1.0f + expf(-z));
  y[i] = x[i] + g * out1[i];
}

// ---------------------------------------------------------------------------
extern "C" void kernel_launch(void* const* d_in, const int* in_sizes, int n_in,
                              void* d_out, int out_size, void* d_ws, size_t ws_size,
                              hipStream_t stream)
{
  const float* x      = (const float*)d_in[0];
  const float* buffer = (const float*)d_in[1];
  const float* Wq     = (const float*)d_in[2];
  const float* Wk     = (const float*)d_in[3];
  const float* Wv     = (const float*)d_in[4];
  const float* Wo     = (const float*)d_in[5];
  const float* Wg     = (const float*)d_in[6];
  const float* bg     = (const float*)d_in[7];
  float* y = (float*)d_out;

  // workspace layout (float units)
  float* ws    = (float*)d_ws;
  float* q     = ws;                        // 262144
  float* qt    = ws + 262144;               // 4194304 (vt aliases after fused)
  float* vt    = qt;
  unsigned short* part_a = (unsigned short*)(ws + 4456448); // 8388608 bf16
  float* ml    = ws + 8650752;              // 8192
  float* o0    = ws + 8658944;              // 262144
  float* o1    = ws + 8921088;              // 262144
  float* partg = ws + 9183232;              // 8 * 262144 = 2097152
  unsigned short* wkT = (unsigned short*)(ws + 11280384);   // 16*2048*128 bf16

  const long S = (long)B_ * D_;

  // 0) WkT[h][e][d] bf16
  transpose_wk<<<dim3(32, 2, 16), 256, 0, stream>>>(Wk, wkT);

  // 1) q = x @ Wq.T   (K=2048, ksplit 8)
  gemm_mfma<false><<<dim3(32, 1, 8), 256, 0, stream>>>(
      x, D_, 0, nullptr, 1 << 30, Wq, D_, 0, partg, D_, 0, S, 256);
  reduce_add_k<<<512, 256, 0, stream>>>(partg, 8, S, S, q);

  // 2) qt[b,h,e] = sum_d q[b,h*128+d] * WkT[h][e][d]   (K=128, per-head)
  gemm_mfma<true><<<dim3(32, 16, 1), 256, 0, stream>>>(
      q, D_, DH_, nullptr, 1 << 30, wkT, DH_, (long)D_ * DH_,
      qt, H_ * D_, D_, 0, DH_);

  // 3) fused flash attention + combine
  fused_attn<<<dim3(B_, 2), 1024, 0, stream>>>(x, buffer, qt, part_a, ml);
  combine_k<<<B_ * H_, 256, 0, stream>>>(part_a, ml, vt);

  // 4) o0[b,h*128+d] = sum_e vt[b,h,e] * Wv[h*128+d,e]  (K=2048, per-head n)
  gemm_mfma<false><<<dim3(2, 16, 8), 256, 0, stream>>>(
      vt, H_ * D_, D_, nullptr, 1 << 30, Wv, D_, (long)DH_ * D_,
      partg, D_, DH_, S, 256);
  reduce_add_k<<<512, 256, 0, stream>>>(partg, 8, S, S, o0);

  // 5) o1 = o0 @ Wo.T
  gemm_mfma<false><<<dim3(32, 1, 8), 256, 0, stream>>>(
      o0, D_, 0, nullptr, 1 << 30, Wo, D_, 0, partg, D_, 0, S, 256);
  reduce_add_k<<<512, 256, 0, stream>>>(partg, 8, S, S, o1);

  // 6) gate: z = concat(x,o1) @ Wg.T + bg   (K=4096, A-switch at 2048)
  gemm_mfma<false><<<dim3(32, 1, 8), 256, 0, stream>>>(
      x, D_, 0, o1, D_, Wg, 2 * D_, 0, partg, D_, 0, S, 512);
  gate_final_k<<<1024, 256, 0, stream>>>(partg, bg, x, o1, y);

  (void)in_sizes; (void)n_in; (void)out_size; (void)ws_size;
}